// Round 18
// baseline (603.382 us; speedup 1.0000x reference)
//
#include <hip/hip_runtime.h>

// MultiHeadedAttention: B=32 L=1024 D=512 H=8 DK=64 W=5
// 5 launches: tcast2 -> proj3 -> localmix2 -> attn -> gemmout.
// GEMM (this round): BM=64 x BN=256, BK=32, 512 thr, 40KB LDS ->
// 4 blocks/CU (32 waves/CU, the occupancy experiment). Same 2-phase loop as
// R15: glds16 B staging, reg-staged A (writeA pre-MFMA), granule-XOR swizzle.
// Attn (R13): swapped-QKT in-register P, no-max base-2 softmax, deferred
// lrun reduce, paired-key b32 V^T staging, dbuf LDS.

typedef __attribute__((ext_vector_type(8))) short bf16x8;
typedef __attribute__((ext_vector_type(4))) float f32x4;

#define MFMA16(a, b, c) __builtin_amdgcn_mfma_f32_16x16x32_bf16((a), (b), (c), 0, 0, 0)

static __device__ __forceinline__ float bf2f(unsigned short u) {
  union { unsigned int i; float f; } v; v.i = ((unsigned int)u) << 16; return v.f;
}
static __device__ __forceinline__ unsigned short f2b(float f) {
  union { float fv; unsigned int i; } v; v.fv = f;
  unsigned int u = v.i;
  return (unsigned short)((u + 0x7fffu + ((u >> 16) & 1u)) >> 16);
}
static __device__ __forceinline__ unsigned int cvtpk(float lo, float hi) {
  unsigned int r;
  asm("v_cvt_pk_bf16_f32 %0, %1, %2" : "=v"(r) : "v"(lo), "v"(hi));
  return r;
}
static __device__ __forceinline__ void glds16(const void* g, void* l) {
  __builtin_amdgcn_global_load_lds(
      (const __attribute__((address_space(1))) unsigned int*)g,
      (__attribute__((address_space(3))) unsigned int*)l, 16, 0, 0);
}
static __device__ __forceinline__ void barrier_lgkm() {
  asm volatile("s_waitcnt lgkmcnt(0)" ::: "memory");
  __builtin_amdgcn_s_barrier();
  __builtin_amdgcn_sched_barrier(0);
}

// ---------------------------------------------------------------- tcast ----
__global__ __launch_bounds__(256) void tcast2_k(const float* __restrict__ s0,
                                                unsigned short* __restrict__ d0,
                                                const float* __restrict__ s1,
                                                unsigned short* __restrict__ d1) {
  int i = blockIdx.x * 256 + threadIdx.x;
  const float* s = s0;
  unsigned short* d = d0;
  if (i >= 262144) { i -= 262144; s = s1; d = d1; }
  int k = i >> 9, n = i & 511;
  d[(size_t)n * 512 + k] = f2b(s[(size_t)k * 512 + n]);
}

// --------------------------------------- 64x256 4-blocks/CU gemm body ----
// LDS: As [2][64][32] bf16 (4KB/buf), Bs [2][256][32] bf16 (16KB/buf) = 40KB.
// Granule (16B) swizzle: slot = g ^ ((row>>1)&3) on both tiles.
// 8 waves: wr=w>>2 (32-row band), wc=w&3 (64-col band). 8 MFMA/wave/K-tile.
template <int AMODE, int OUTMODE>
__device__ __forceinline__ void gemm64(const void* __restrict__ A_,
                                       const unsigned short* __restrict__ BT,
                                       const float* __restrict__ bias,
                                       void* __restrict__ out_, int bm, int bn) {
  __shared__ unsigned short As[2][64 * 32];
  __shared__ unsigned short Bs[2][256 * 32];
  const int tid = threadIdx.x;  // 0..511
  const int w = tid >> 6, l = tid & 63;
  const int lg = l >> 4, lr = l & 15;
  const int wr = w >> 2, wc = w & 3;
  const int rowbase = bm * 64;
  const int colbase = bn * 256;

  const int arow = tid >> 2, akq = tid & 3;
  const int aslot = (akq ^ ((arow >> 1) & 3)) << 3;

  f32x4 acc[2][4];
#pragma unroll
  for (int m = 0; m < 2; ++m)
#pragma unroll
    for (int n = 0; n < 4; ++n) acc[m][n] = (f32x4){0.f, 0.f, 0.f, 0.f};

  float4 fa0[2], fa1[2];
  uint4 ba0, ba1;

  auto loadA = [&](int t, float4* df, uint4& db) {
    if constexpr (AMODE == 0) {
      const float* p = (const float*)A_ + (size_t)(rowbase + arow) * 512 + t * 32 + akq * 8;
      df[0] = ((const float4*)p)[0];
      df[1] = ((const float4*)p)[1];
    } else {
      db = *(const uint4*)((const unsigned short*)A_ + (size_t)(rowbase + arow) * 512 + t * 32 + akq * 8);
    }
  };
  auto writeA = [&](int buf, const float4* df, const uint4& db) {
    uint4 u;
    if constexpr (AMODE == 0) {
      u.x = cvtpk(df[0].x, df[0].y); u.y = cvtpk(df[0].z, df[0].w);
      u.z = cvtpk(df[1].x, df[1].y); u.w = cvtpk(df[1].z, df[1].w);
    } else {
      u = db;
    }
    *(uint4*)&As[buf][arow * 32 + aslot] = u;
  };
  auto stageB = [&](int t, int buf) {
#pragma unroll
    for (int j = 0; j < 2; ++j) {
      const int jr = j * 128 + w * 16 + (l >> 2);  // B row (C col) 0..255
      const int g = (l & 3) ^ ((jr >> 1) & 3);
      glds16(BT + (size_t)(colbase + jr) * 512 + t * 32 + g * 8,
             &Bs[buf][(j * 128 + w * 16) * 32]);
    }
  };

  if (w < 4) loadA(0, fa0, ba0);
  stageB(0, 0);
  if (w < 4) {
    writeA(0, fa0, ba0);
    loadA(1, fa1, ba1);
  }
  __syncthreads();

  for (int t = 0; t < 16; ++t) {
    const int cur = t & 1;
    if (t < 15) stageB(t + 1, cur ^ 1);
    if (w < 4 && t < 14) {
      if (cur == 0) loadA(t + 2, fa0, ba0);
      else          loadA(t + 2, fa1, ba1);
    }
    // stage A(t+1) early: ds_writes drain during the MFMA phase below
    if (w < 4 && t < 15) {
      if (cur == 0) writeA(1, fa1, ba1);
      else          writeA(0, fa0, ba0);
    }
    bf16x8 af[2];
#pragma unroll
    for (int m = 0; m < 2; ++m) {
      const int r = wr * 32 + m * 16 + lr;
      af[m] = *(const bf16x8*)&As[cur][r * 32 + ((lg ^ ((r >> 1) & 3)) << 3)];
    }
    bf16x8 bf[4];
#pragma unroll
    for (int ni = 0; ni < 4; ++ni) {
      const int c = wc * 64 + ni * 16 + lr;
      bf[ni] = *(const bf16x8*)&Bs[cur][c * 32 + ((lg ^ ((c >> 1) & 3)) << 3)];
    }
    __builtin_amdgcn_s_setprio(1);
#pragma unroll
    for (int m = 0; m < 2; ++m)
#pragma unroll
      for (int ni = 0; ni < 4; ++ni)
        acc[m][ni] = MFMA16(af[m], bf[ni], acc[m][ni]);
    __builtin_amdgcn_s_setprio(0);
    __syncthreads();
  }

#pragma unroll
  for (int m = 0; m < 2; ++m)
#pragma unroll
    for (int ni = 0; ni < 4; ++ni) {
      const int grow0 = rowbase + wr * 32 + m * 16 + 4 * lg;
      const int gcol = colbase + wc * 64 + ni * 16 + lr;
      const float bs = bias[gcol];
#pragma unroll
      for (int r = 0; r < 4; ++r) {
        float v = acc[m][ni][r] + bs;
        if constexpr (OUTMODE == 0)
          ((unsigned short*)out_)[(size_t)(grow0 + r) * 512 + gcol] = f2b(v);
        else
          ((float*)out_)[(size_t)(grow0 + r) * 512 + gcol] = v;
      }
    }
}

// Fused q/k/v projection: 3072 blocks (1024 per tensor: 512 bm x 2 bn),
// XCD-swizzled; bn in the low bit so adjacent blocks share A rows.
__global__ __launch_bounds__(512, 8) void proj3_k(const float* __restrict__ q,
                                                  const float* __restrict__ k,
                                                  const float* __restrict__ v,
                                                  const unsigned short* __restrict__ W0T,
                                                  const float* __restrict__ b0,
                                                  unsigned short* __restrict__ Pq,
                                                  unsigned short* __restrict__ Pk,
                                                  unsigned short* __restrict__ Pv) {
  const int wg = (blockIdx.x & 7) * 384 + (blockIdx.x >> 3);
  const int t = wg >> 10, rem = wg & 1023;
  const float* A = t == 0 ? q : t == 1 ? k : v;
  unsigned short* O = t == 0 ? Pq : t == 1 ? Pk : Pv;
  gemm64<0, 0>(A, W0T, b0, O, rem >> 1, rem & 1);
}

__global__ __launch_bounds__(512, 8) void gemmout_k(const unsigned short* __restrict__ A,
                                                    const unsigned short* __restrict__ WoT,
                                                    const float* __restrict__ bout,
                                                    float* __restrict__ out) {
  const int wg = (blockIdx.x & 7) * 128 + (blockIdx.x >> 3);
  gemm64<1, 1>(A, WoT, bout, out, wg >> 1, wg & 1);
}

// ------------------------------------------------------------- localmix ----
__global__ __launch_bounds__(256) void localmix2_k(const unsigned short* __restrict__ Pq,
                                                   const unsigned short* __restrict__ Pk,
                                                   const float* __restrict__ b0,
                                                   unsigned short* __restrict__ Qm,
                                                   unsigned short* __restrict__ Km) {
  const int w = threadIdx.x >> 6, lane = threadIdx.x & 63;
  const int pp = blockIdx.x * 4 + w;
  const unsigned short* P;
  unsigned short* out;
  float outscale;
  int p;
  if (pp < 32768) { P = Pq; out = Qm; outscale = 0.18033688011112042f; p = pp; }
  else            { P = Pk; out = Km; outscale = 1.0f; p = pp - 32768; }
  const int l = p & 1023;
  const int d0 = lane * 8;

  float win[5][8];
#pragma unroll
  for (int j = 0; j < 5; ++j) {
    const int src = l - 4 + j;
    if (src >= 0) {
      const uint4 v = *(const uint4*)(P + (size_t)(p - 4 + j) * 512 + d0);
      const unsigned short* u = (const unsigned short*)&v;
#pragma unroll
      for (int i = 0; i < 8; ++i) win[j][i] = bf2f(u[i]);
    } else {
      const float4 f0 = *(const float4*)(b0 + d0);
      const float4 f1 = *(const float4*)(b0 + d0 + 4);
      win[j][0] = f0.x; win[j][1] = f0.y; win[j][2] = f0.z; win[j][3] = f0.w;
      win[j][4] = f1.x; win[j][5] = f1.y; win[j][6] = f1.z; win[j][7] = f1.w;
    }
  }
  float s[5];
#pragma unroll
  for (int j = 0; j < 5; ++j) {
    float t = 0.f;
#pragma unroll
    for (int i = 0; i < 8; ++i) t += win[4][i] * win[j][i];
    s[j] = t;
  }
#pragma unroll
  for (int off = 1; off < 64; off <<= 1)
#pragma unroll
    for (int j = 0; j < 5; ++j) s[j] += __shfl_xor(s[j], off, 64);
  const float sc = 0.04419417382415922f;
  float mx = -1e30f;
#pragma unroll
  for (int j = 0; j < 5; ++j) { s[j] *= sc; mx = fmaxf(mx, s[j]); }
  float e[5], sum = 0.f;
#pragma unroll
  for (int j = 0; j < 5; ++j) { e[j] = __expf(s[j] - mx); sum += e[j]; }
  const float inv = 1.f / sum;
  __attribute__((ext_vector_type(8))) unsigned short o;
#pragma unroll
  for (int i = 0; i < 8; ++i) {
    float a = 0.f;
#pragma unroll
    for (int j = 0; j < 5; ++j) a += e[j] * win[j][i];
    o[i] = f2b(a * inv * outscale);
  }
  *(__attribute__((ext_vector_type(8))) unsigned short*)(out + (size_t)p * 512 + d0) = o;
}

// ----------------------------------------------------------------- attn ----
__global__ __launch_bounds__(256) void attn_k(const unsigned short* __restrict__ Q,
                                              const unsigned short* __restrict__ K,
                                              const unsigned short* __restrict__ V,
                                              unsigned short* __restrict__ AO) {
  __shared__ unsigned short Ks[2][64 * 64];
  __shared__ unsigned short Vt[2][64 * 64];
  const int tid = threadIdx.x;
  const int w = tid >> 6, l = tid & 63;
  const int lg = l >> 4, lr = l & 15;
  const int wg = (blockIdx.x & 7) * 256 + (blockIdx.x >> 3);
  const int qt = wg & 7, bh = wg >> 3;
  const int h = bh & 7, b = bh >> 3;
  const size_t base = (size_t)(b * 1024) * 512 + h * 64;
  const unsigned short* Qb = Q + base + (size_t)(qt * 128) * 512;
  const unsigned short* Kb = K + base;
  const unsigned short* Vb = V + base;

  bf16x8 qf[2][2];
#pragma unroll
  for (int rb = 0; rb < 2; ++rb)
#pragma unroll
    for (int ks = 0; ks < 2; ++ks)
      qf[rb][ks] = *(const bf16x8*)(Qb + (size_t)(w * 32 + rb * 16 + lr) * 512 + ks * 32 + lg * 8);

  f32x4 acc[2][4];
#pragma unroll
  for (int rb = 0; rb < 2; ++rb)
#pragma unroll
    for (int nb = 0; nb < 4; ++nb) acc[rb][nb] = (f32x4){0.f, 0.f, 0.f, 0.f};
  float lsum[2] = {0.f, 0.f};

  const int sk_row = tid >> 2, sk_seg = tid & 3;
  const int r7 = sk_row & 7;
  const int kp = tid & 31, dg = tid >> 5;
  const int k0v = 2 * kp;
  const int vpos0 = (k0v & 32) + ((k0v >> 2) & 3) * 8 + ((k0v >> 4) & 1) * 4 + (k0v & 3);
  const int vg = vpos0 >> 3, vp = vpos0 & 7;

  uint4 kr0, kr1, vr0, vr1;
  auto loadT = [&](int t) {
    const uint4* ksrc = (const uint4*)(Kb + (size_t)(t * 64 + sk_row) * 512 + sk_seg * 16);
    kr0 = ksrc[0]; kr1 = ksrc[1];
    vr0 = *(const uint4*)(Vb + (size_t)(t * 64 + k0v) * 512 + dg * 8);
    vr1 = *(const uint4*)(Vb + (size_t)(t * 64 + k0v + 1) * 512 + dg * 8);
  };
  auto writeT = [&](int bufi) {
    unsigned short* kd = Ks[bufi];
    unsigned short* vd = Vt[bufi];
    *(uint4*)&kd[sk_row * 64 + (((2 * sk_seg) ^ r7) << 3)] = kr0;
    *(uint4*)&kd[sk_row * 64 + (((2 * sk_seg + 1) ^ r7) << 3)] = kr1;
    const unsigned short* u0 = (const unsigned short*)&vr0;
    const unsigned short* u1 = (const unsigned short*)&vr1;
#pragma unroll
    for (int j = 0; j < 8; ++j) {
      const int d = 8 * dg + j;
      const unsigned int pack = (unsigned int)u0[j] | ((unsigned int)u1[j] << 16);
      *(unsigned int*)&vd[d * 64 + ((vg ^ (d & 7)) << 3) + vp] = pack;
    }
  };

  loadT(0);
  writeT(0);
  loadT(1);
  barrier_lgkm();

  const int swz0 = (lg ^ (lr & 7)) << 3, swz1 = ((4 + lg) ^ (lr & 7)) << 3;

  for (int it = 0; it < 16; ++it) {
    const int cur = it & 1;
    f32x4 sf[2][4];
    __builtin_amdgcn_s_setprio(1);
#pragma unroll
    for (int kb = 0; kb < 4; ++kb) {
      const int krow = (kb * 16 + lr) * 64;
      bf16x8 kf0 = *(const bf16x8*)&Ks[cur][krow + swz0];
      bf16x8 kf1 = *(const bf16x8*)&Ks[cur][krow + swz1];
#pragma unroll
      for (int rb = 0; rb < 2; ++rb) {
        f32x4 z = (f32x4){0.f, 0.f, 0.f, 0.f};
        z = MFMA16(kf0, qf[rb][0], z);
        z = MFMA16(kf1, qf[rb][1], z);
        sf[rb][kb] = z;
      }
    }
    __builtin_amdgcn_s_setprio(0);

    if (it < 15) writeT((it + 1) & 1);
    if (it < 14) loadT(it + 2);

#pragma unroll
    for (int rb = 0; rb < 2; ++rb) {
#pragma unroll
      for (int kb = 0; kb < 4; ++kb)
#pragma unroll
        for (int r = 0; r < 4; ++r)
          sf[rb][kb][r] = __builtin_amdgcn_exp2f(sf[rb][kb][r]);
      float s0 = (sf[rb][0][0] + sf[rb][0][1]) + (sf[rb][0][2] + sf[rb][0][3]);
      float s1 = (sf[rb][1][0] + sf[rb][1][1]) + (sf[rb][1][2] + sf[rb][1][3]);
      float s2 = (sf[rb][2][0] + sf[rb][2][1]) + (sf[rb][2][2] + sf[rb][2][3]);
      float s3 = (sf[rb][3][0] + sf[rb][3][1]) + (sf[rb][3][2] + sf[rb][3][3]);
      lsum[rb] += (s0 + s1) + (s2 + s3);
    }

    union { uint4 d; bf16x8 v; } pa[2][2];
#pragma unroll
    for (int rb = 0; rb < 2; ++rb)
#pragma unroll
      for (int t2 = 0; t2 < 2; ++t2) {
        pa[rb][t2].d.x = cvtpk(sf[rb][2 * t2][0], sf[rb][2 * t2][1]);
        pa[rb][t2].d.y = cvtpk(sf[rb][2 * t2][2], sf[rb][2 * t2][3]);
        pa[rb][t2].d.z = cvtpk(sf[rb][2 * t2 + 1][0], sf[rb][2 * t2 + 1][1]);
        pa[rb][t2].d.w = cvtpk(sf[rb][2 * t2 + 1][2], sf[rb][2 * t2 + 1][3]);
      }

    __builtin_amdgcn_s_setprio(1);
#pragma unroll
    for (int t2 = 0; t2 < 2; ++t2) {
      bf16x8 vf[4];
#pragma unroll
      for (int nb = 0; nb < 4; ++nb) {
        const int vrow = (nb * 16 + lr) * 64;
        vf[nb] = *(const bf16x8*)&Vt[cur][vrow + (((4 * t2 + lg) ^ (lr & 7)) << 3)];
      }
#pragma unroll
      for (int rb = 0; rb < 2; ++rb)
#pragma unroll
        for (int nb = 0; nb < 4; ++nb) acc[rb][nb] = MFMA16(pa[rb][t2].v, vf[nb], acc[rb][nb]);
    }
    __builtin_amdgcn_s_setprio(0);
    if (it < 15) barrier_lgkm();
  }

#pragma unroll
  for (int rb = 0; rb < 2; ++rb) {
    float tsum = lsum[rb];
    tsum += __shfl_xor(tsum, 16, 64);
    tsum += __shfl_xor(tsum, 32, 64);
    const float rec = 1.f / tsum;
    float lv[4];
#pragma unroll
    for (int r = 0; r < 4; ++r) lv[r] = __shfl(rec, lg * 4 + r, 64);
#pragma unroll
    for (int nb = 0; nb < 4; ++nb) {
      const int gcol = nb * 16 + lr;
#pragma unroll
      for (int r = 0; r < 4; ++r) {
        const int grow = qt * 128 + w * 32 + rb * 16 + 4 * lg + r;
        AO[base + (size_t)grow * 512 + gcol] = f2b(acc[rb][nb][r] * lv[r]);
      }
    }
  }
}

// -------------------------------------------------------------- launch -----
extern "C" void kernel_launch(void* const* d_in, const int* in_sizes, int n_in,
                              void* d_out, int out_size, void* d_ws, size_t ws_size,
                              hipStream_t stream) {
  const float* query = (const float*)d_in[0];
  const float* key   = (const float*)d_in[1];
  const float* value = (const float*)d_in[2];
  const float* W0    = (const float*)d_in[3];
  const float* b0    = (const float*)d_in[4];
  const float* Wout  = (const float*)d_in[5];
  const float* bout  = (const float*)d_in[6];
  float* out = (float*)d_out;

  char* ws = (char*)d_ws;
  const size_t PSZ = (size_t)32768 * 512 * 2;
  unsigned short* Pq  = (unsigned short*)(ws);            // later reused as AO
  unsigned short* Pk  = (unsigned short*)(ws + PSZ);
  unsigned short* Pv  = (unsigned short*)(ws + 2 * PSZ);
  unsigned short* Qm  = (unsigned short*)(ws + 3 * PSZ);
  unsigned short* Km  = (unsigned short*)(ws + 4 * PSZ);
  unsigned short* W0T = (unsigned short*)(ws + 5 * PSZ);
  unsigned short* WoT = (unsigned short*)(ws + 5 * PSZ + 524288);

  tcast2_k<<<2048, 256, 0, stream>>>(W0, W0T, Wout, WoT);
  proj3_k<<<3072, 512, 0, stream>>>(query, key, value, W0T, b0, Pq, Pk, Pv);
  localmix2_k<<<16384, 256, 0, stream>>>(Pq, Pk, b0, Qm, Km);
  attn_k<<<2048, 256, 0, stream>>>(Qm, Km, Pv, Pq /*AO*/);
  gemmout_k<<<1024, 512, 0, stream>>>(Pq, WoT, bout, out);
}

// Round 19
// 276.465 us; speedup vs baseline: 2.1825x; 2.1825x over previous
//
#include <hip/hip_runtime.h>

// MultiHeadedAttention: B=32 L=1024 D=512 H=8 DK=64 W=5
// 5 launches: tcast2 -> proj3 -> localmix2 -> attn -> gemmout.
// GEMM (R15, best measured, final): BM=64 x BN=512 (A read once), BK=32,
// 512 thr, 72KB LDS, 2 blocks/CU; writeA hoisted pre-MFMA so lgkm drains
// under compute. Attn (R13): swapped-QKT in-register P, no-max base-2
// softmax, deferred lrun reduce, paired-key b32 V^T staging, dbuf LDS.

typedef __attribute__((ext_vector_type(8))) short bf16x8;
typedef __attribute__((ext_vector_type(4))) float f32x4;

#define MFMA16(a, b, c) __builtin_amdgcn_mfma_f32_16x16x32_bf16((a), (b), (c), 0, 0, 0)

static __device__ __forceinline__ float bf2f(unsigned short u) {
  union { unsigned int i; float f; } v; v.i = ((unsigned int)u) << 16; return v.f;
}
static __device__ __forceinline__ unsigned short f2b(float f) {
  union { float fv; unsigned int i; } v; v.fv = f;
  unsigned int u = v.i;
  return (unsigned short)((u + 0x7fffu + ((u >> 16) & 1u)) >> 16);
}
static __device__ __forceinline__ unsigned int cvtpk(float lo, float hi) {
  unsigned int r;
  asm("v_cvt_pk_bf16_f32 %0, %1, %2" : "=v"(r) : "v"(lo), "v"(hi));
  return r;
}
static __device__ __forceinline__ void glds16(const void* g, void* l) {
  __builtin_amdgcn_global_load_lds(
      (const __attribute__((address_space(1))) unsigned int*)g,
      (__attribute__((address_space(3))) unsigned int*)l, 16, 0, 0);
}
static __device__ __forceinline__ void barrier_lgkm() {
  asm volatile("s_waitcnt lgkmcnt(0)" ::: "memory");
  __builtin_amdgcn_s_barrier();
  __builtin_amdgcn_sched_barrier(0);
}

// ---------------------------------------------------------------- tcast ----
__global__ __launch_bounds__(256) void tcast2_k(const float* __restrict__ s0,
                                                unsigned short* __restrict__ d0,
                                                const float* __restrict__ s1,
                                                unsigned short* __restrict__ d1) {
  int i = blockIdx.x * 256 + threadIdx.x;
  const float* s = s0;
  unsigned short* d = d0;
  if (i >= 262144) { i -= 262144; s = s1; d = d1; }
  int k = i >> 9, n = i & 511;
  d[(size_t)n * 512 + k] = f2b(s[(size_t)k * 512 + n]);
}

// ------------------------------------------- 64x512 A-read-once gemm body ----
template <int AMODE, int OUTMODE>
__device__ __forceinline__ void gemm64(const void* __restrict__ A_,
                                       const unsigned short* __restrict__ BT,
                                       const float* __restrict__ bias,
                                       void* __restrict__ out_, int bm) {
  __shared__ unsigned short As[2][64 * 32];
  __shared__ unsigned short Bs[2][512 * 32];
  const int tid = threadIdx.x;  // 0..511
  const int w = tid >> 6, l = tid & 63;
  const int lg = l >> 4, lr = l & 15;
  const int wr = w >> 2, wc = w & 3;
  const int rowbase = bm * 64;

  const int arow = tid >> 2, akq = tid & 3;
  const int aslot = (akq ^ ((arow >> 1) & 3)) << 3;

  f32x4 acc[2][8];
#pragma unroll
  for (int m = 0; m < 2; ++m)
#pragma unroll
    for (int n = 0; n < 8; ++n) acc[m][n] = (f32x4){0.f, 0.f, 0.f, 0.f};

  float4 fa0[2], fa1[2];
  uint4 ba0, ba1;

  auto loadA = [&](int t, float4* df, uint4& db) {
    if constexpr (AMODE == 0) {
      const float* p = (const float*)A_ + (size_t)(rowbase + arow) * 512 + t * 32 + akq * 8;
      df[0] = ((const float4*)p)[0];
      df[1] = ((const float4*)p)[1];
    } else {
      db = *(const uint4*)((const unsigned short*)A_ + (size_t)(rowbase + arow) * 512 + t * 32 + akq * 8);
    }
  };
  auto writeA = [&](int buf, const float4* df, const uint4& db) {
    uint4 u;
    if constexpr (AMODE == 0) {
      u.x = cvtpk(df[0].x, df[0].y); u.y = cvtpk(df[0].z, df[0].w);
      u.z = cvtpk(df[1].x, df[1].y); u.w = cvtpk(df[1].z, df[1].w);
    } else {
      u = db;
    }
    *(uint4*)&As[buf][arow * 32 + aslot] = u;
  };
  auto stageB = [&](int t, int buf) {
#pragma unroll
    for (int j = 0; j < 4; ++j) {
      const int jr = j * 128 + w * 16 + (l >> 2);
      const int g = (l & 3) ^ ((jr >> 1) & 3);
      glds16(BT + (size_t)jr * 512 + t * 32 + g * 8,
             &Bs[buf][(j * 128 + w * 16) * 32]);
    }
  };

  if (w < 4) loadA(0, fa0, ba0);
  stageB(0, 0);
  if (w < 4) {
    writeA(0, fa0, ba0);
    loadA(1, fa1, ba1);
  }
  __syncthreads();

  for (int t = 0; t < 16; ++t) {
    const int cur = t & 1;
    if (t < 15) stageB(t + 1, cur ^ 1);
    if (w < 4 && t < 14) {
      if (cur == 0) loadA(t + 2, fa0, ba0);
      else          loadA(t + 2, fa1, ba1);
    }
    // stage A(t+1) early: ds_writes drain during the MFMA phase below
    if (w < 4 && t < 15) {
      if (cur == 0) writeA(1, fa1, ba1);
      else          writeA(0, fa0, ba0);
    }
    bf16x8 af[2];
#pragma unroll
    for (int m = 0; m < 2; ++m) {
      const int r = wr * 32 + m * 16 + lr;
      af[m] = *(const bf16x8*)&As[cur][r * 32 + ((lg ^ ((r >> 1) & 3)) << 3)];
    }
#pragma unroll
    for (int h = 0; h < 2; ++h) {
      bf16x8 bf[4];
#pragma unroll
      for (int ni = 0; ni < 4; ++ni) {
        const int c = wc * 128 + (h * 4 + ni) * 16 + lr;
        bf[ni] = *(const bf16x8*)&Bs[cur][c * 32 + ((lg ^ ((c >> 1) & 3)) << 3)];
      }
      __builtin_amdgcn_s_setprio(1);
#pragma unroll
      for (int m = 0; m < 2; ++m)
#pragma unroll
        for (int ni = 0; ni < 4; ++ni)
          acc[m][h * 4 + ni] = MFMA16(af[m], bf[ni], acc[m][h * 4 + ni]);
      __builtin_amdgcn_s_setprio(0);
    }
    __syncthreads();
  }

#pragma unroll
  for (int m = 0; m < 2; ++m)
#pragma unroll
    for (int ni = 0; ni < 8; ++ni) {
      const int grow0 = rowbase + wr * 32 + m * 16 + 4 * lg;
      const int gcol = wc * 128 + ni * 16 + lr;
      const float bs = bias[gcol];
#pragma unroll
      for (int r = 0; r < 4; ++r) {
        float v = acc[m][ni][r] + bs;
        if constexpr (OUTMODE == 0)
          ((unsigned short*)out_)[(size_t)(grow0 + r) * 512 + gcol] = f2b(v);
        else
          ((float*)out_)[(size_t)(grow0 + r) * 512 + gcol] = v;
      }
    }
}

__global__ __launch_bounds__(512, 4) void proj3_k(const float* __restrict__ q,
                                                  const float* __restrict__ k,
                                                  const float* __restrict__ v,
                                                  const unsigned short* __restrict__ W0T,
                                                  const float* __restrict__ b0,
                                                  unsigned short* __restrict__ Pq,
                                                  unsigned short* __restrict__ Pk,
                                                  unsigned short* __restrict__ Pv) {
  const int wg = (blockIdx.x & 7) * 192 + (blockIdx.x >> 3);
  const int t = wg >> 9, rem = wg & 511;
  const float* A = t == 0 ? q : t == 1 ? k : v;
  unsigned short* O = t == 0 ? Pq : t == 1 ? Pk : Pv;
  gemm64<0, 0>(A, W0T, b0, O, rem);
}

__global__ __launch_bounds__(512, 4) void gemmout_k(const unsigned short* __restrict__ A,
                                                    const unsigned short* __restrict__ WoT,
                                                    const float* __restrict__ bout,
                                                    float* __restrict__ out) {
  const int wg = (blockIdx.x & 7) * 64 + (blockIdx.x >> 3);
  gemm64<1, 1>(A, WoT, bout, out, wg);
}

// ------------------------------------------------------------- localmix ----
__global__ __launch_bounds__(256) void localmix2_k(const unsigned short* __restrict__ Pq,
                                                   const unsigned short* __restrict__ Pk,
                                                   const float* __restrict__ b0,
                                                   unsigned short* __restrict__ Qm,
                                                   unsigned short* __restrict__ Km) {
  const int w = threadIdx.x >> 6, lane = threadIdx.x & 63;
  const int pp = blockIdx.x * 4 + w;
  const unsigned short* P;
  unsigned short* out;
  float outscale;
  int p;
  if (pp < 32768) { P = Pq; out = Qm; outscale = 0.18033688011112042f; p = pp; }
  else            { P = Pk; out = Km; outscale = 1.0f; p = pp - 32768; }
  const int l = p & 1023;
  const int d0 = lane * 8;

  float win[5][8];
#pragma unroll
  for (int j = 0; j < 5; ++j) {
    const int src = l - 4 + j;
    if (src >= 0) {
      const uint4 v = *(const uint4*)(P + (size_t)(p - 4 + j) * 512 + d0);
      const unsigned short* u = (const unsigned short*)&v;
#pragma unroll
      for (int i = 0; i < 8; ++i) win[j][i] = bf2f(u[i]);
    } else {
      const float4 f0 = *(const float4*)(b0 + d0);
      const float4 f1 = *(const float4*)(b0 + d0 + 4);
      win[j][0] = f0.x; win[j][1] = f0.y; win[j][2] = f0.z; win[j][3] = f0.w;
      win[j][4] = f1.x; win[j][5] = f1.y; win[j][6] = f1.z; win[j][7] = f1.w;
    }
  }
  float s[5];
#pragma unroll
  for (int j = 0; j < 5; ++j) {
    float t = 0.f;
#pragma unroll
    for (int i = 0; i < 8; ++i) t += win[4][i] * win[j][i];
    s[j] = t;
  }
#pragma unroll
  for (int off = 1; off < 64; off <<= 1)
#pragma unroll
    for (int j = 0; j < 5; ++j) s[j] += __shfl_xor(s[j], off, 64);
  const float sc = 0.04419417382415922f;
  float mx = -1e30f;
#pragma unroll
  for (int j = 0; j < 5; ++j) { s[j] *= sc; mx = fmaxf(mx, s[j]); }
  float e[5], sum = 0.f;
#pragma unroll
  for (int j = 0; j < 5; ++j) { e[j] = __expf(s[j] - mx); sum += e[j]; }
  const float inv = 1.f / sum;
  __attribute__((ext_vector_type(8))) unsigned short o;
#pragma unroll
  for (int i = 0; i < 8; ++i) {
    float a = 0.f;
#pragma unroll
    for (int j = 0; j < 5; ++j) a += e[j] * win[j][i];
    o[i] = f2b(a * inv * outscale);
  }
  *(__attribute__((ext_vector_type(8))) unsigned short*)(out + (size_t)p * 512 + d0) = o;
}

// ----------------------------------------------------------------- attn ----
__global__ __launch_bounds__(256) void attn_k(const unsigned short* __restrict__ Q,
                                              const unsigned short* __restrict__ K,
                                              const unsigned short* __restrict__ V,
                                              unsigned short* __restrict__ AO) {
  __shared__ unsigned short Ks[2][64 * 64];
  __shared__ unsigned short Vt[2][64 * 64];
  const int tid = threadIdx.x;
  const int w = tid >> 6, l = tid & 63;
  const int lg = l >> 4, lr = l & 15;
  const int wg = (blockIdx.x & 7) * 256 + (blockIdx.x >> 3);
  const int qt = wg & 7, bh = wg >> 3;
  const int h = bh & 7, b = bh >> 3;
  const size_t base = (size_t)(b * 1024) * 512 + h * 64;
  const unsigned short* Qb = Q + base + (size_t)(qt * 128) * 512;
  const unsigned short* Kb = K + base;
  const unsigned short* Vb = V + base;

  bf16x8 qf[2][2];
#pragma unroll
  for (int rb = 0; rb < 2; ++rb)
#pragma unroll
    for (int ks = 0; ks < 2; ++ks)
      qf[rb][ks] = *(const bf16x8*)(Qb + (size_t)(w * 32 + rb * 16 + lr) * 512 + ks * 32 + lg * 8);

  f32x4 acc[2][4];
#pragma unroll
  for (int rb = 0; rb < 2; ++rb)
#pragma unroll
    for (int nb = 0; nb < 4; ++nb) acc[rb][nb] = (f32x4){0.f, 0.f, 0.f, 0.f};
  float lsum[2] = {0.f, 0.f};

  const int sk_row = tid >> 2, sk_seg = tid & 3;
  const int r7 = sk_row & 7;
  const int kp = tid & 31, dg = tid >> 5;
  const int k0v = 2 * kp;
  const int vpos0 = (k0v & 32) + ((k0v >> 2) & 3) * 8 + ((k0v >> 4) & 1) * 4 + (k0v & 3);
  const int vg = vpos0 >> 3, vp = vpos0 & 7;

  uint4 kr0, kr1, vr0, vr1;
  auto loadT = [&](int t) {
    const uint4* ksrc = (const uint4*)(Kb + (size_t)(t * 64 + sk_row) * 512 + sk_seg * 16);
    kr0 = ksrc[0]; kr1 = ksrc[1];
    vr0 = *(const uint4*)(Vb + (size_t)(t * 64 + k0v) * 512 + dg * 8);
    vr1 = *(const uint4*)(Vb + (size_t)(t * 64 + k0v + 1) * 512 + dg * 8);
  };
  auto writeT = [&](int bufi) {
    unsigned short* kd = Ks[bufi];
    unsigned short* vd = Vt[bufi];
    *(uint4*)&kd[sk_row * 64 + (((2 * sk_seg) ^ r7) << 3)] = kr0;
    *(uint4*)&kd[sk_row * 64 + (((2 * sk_seg + 1) ^ r7) << 3)] = kr1;
    const unsigned short* u0 = (const unsigned short*)&vr0;
    const unsigned short* u1 = (const unsigned short*)&vr1;
#pragma unroll
    for (int j = 0; j < 8; ++j) {
      const int d = 8 * dg + j;
      const unsigned int pack = (unsigned int)u0[j] | ((unsigned int)u1[j] << 16);
      *(unsigned int*)&vd[d * 64 + ((vg ^ (d & 7)) << 3) + vp] = pack;
    }
  };

  loadT(0);
  writeT(0);
  loadT(1);
  barrier_lgkm();

  const int swz0 = (lg ^ (lr & 7)) << 3, swz1 = ((4 + lg) ^ (lr & 7)) << 3;

  for (int it = 0; it < 16; ++it) {
    const int cur = it & 1;
    f32x4 sf[2][4];
    __builtin_amdgcn_s_setprio(1);
#pragma unroll
    for (int kb = 0; kb < 4; ++kb) {
      const int krow = (kb * 16 + lr) * 64;
      bf16x8 kf0 = *(const bf16x8*)&Ks[cur][krow + swz0];
      bf16x8 kf1 = *(const bf16x8*)&Ks[cur][krow + swz1];
#pragma unroll
      for (int rb = 0; rb < 2; ++rb) {
        f32x4 z = (f32x4){0.f, 0.f, 0.f, 0.f};
        z = MFMA16(kf0, qf[rb][0], z);
        z = MFMA16(kf1, qf[rb][1], z);
        sf[rb][kb] = z;
      }
    }
    __builtin_amdgcn_s_setprio(0);

    if (it < 15) writeT((it + 1) & 1);
    if (it < 14) loadT(it + 2);

#pragma unroll
    for (int rb = 0; rb < 2; ++rb) {
#pragma unroll
      for (int kb = 0; kb < 4; ++kb)
#pragma unroll
        for (int r = 0; r < 4; ++r)
          sf[rb][kb][r] = __builtin_amdgcn_exp2f(sf[rb][kb][r]);
      float s0 = (sf[rb][0][0] + sf[rb][0][1]) + (sf[rb][0][2] + sf[rb][0][3]);
      float s1 = (sf[rb][1][0] + sf[rb][1][1]) + (sf[rb][1][2] + sf[rb][1][3]);
      float s2 = (sf[rb][2][0] + sf[rb][2][1]) + (sf[rb][2][2] + sf[rb][2][3]);
      float s3 = (sf[rb][3][0] + sf[rb][3][1]) + (sf[rb][3][2] + sf[rb][3][3]);
      lsum[rb] += (s0 + s1) + (s2 + s3);
    }

    union { uint4 d; bf16x8 v; } pa[2][2];
#pragma unroll
    for (int rb = 0; rb < 2; ++rb)
#pragma unroll
      for (int t2 = 0; t2 < 2; ++t2) {
        pa[rb][t2].d.x = cvtpk(sf[rb][2 * t2][0], sf[rb][2 * t2][1]);
        pa[rb][t2].d.y = cvtpk(sf[rb][2 * t2][2], sf[rb][2 * t2][3]);
        pa[rb][t2].d.z = cvtpk(sf[rb][2 * t2 + 1][0], sf[rb][2 * t2 + 1][1]);
        pa[rb][t2].d.w = cvtpk(sf[rb][2 * t2 + 1][2], sf[rb][2 * t2 + 1][3]);
      }

    __builtin_amdgcn_s_setprio(1);
#pragma unroll
    for (int t2 = 0; t2 < 2; ++t2) {
      bf16x8 vf[4];
#pragma unroll
      for (int nb = 0; nb < 4; ++nb) {
        const int vrow = (nb * 16 + lr) * 64;
        vf[nb] = *(const bf16x8*)&Vt[cur][vrow + (((4 * t2 + lg) ^ (lr & 7)) << 3)];
      }
#pragma unroll
      for (int rb = 0; rb < 2; ++rb)
#pragma unroll
        for (int nb = 0; nb < 4; ++nb) acc[rb][nb] = MFMA16(pa[rb][t2].v, vf[nb], acc[rb][nb]);
    }
    __builtin_amdgcn_s_setprio(0);
    if (it < 15) barrier_lgkm();
  }

#pragma unroll
  for (int rb = 0; rb < 2; ++rb) {
    float tsum = lsum[rb];
    tsum += __shfl_xor(tsum, 16, 64);
    tsum += __shfl_xor(tsum, 32, 64);
    const float rec = 1.f / tsum;
    float lv[4];
#pragma unroll
    for (int r = 0; r < 4; ++r) lv[r] = __shfl(rec, lg * 4 + r, 64);
#pragma unroll
    for (int nb = 0; nb < 4; ++nb) {
      const int gcol = nb * 16 + lr;
#pragma unroll
      for (int r = 0; r < 4; ++r) {
        const int grow = qt * 128 + w * 32 + rb * 16 + 4 * lg + r;
        AO[base + (size_t)grow * 512 + gcol] = f2b(acc[rb][nb][r] * lv[r]);
      }
    }
  }
}

// -------------------------------------------------------------- launch -----
extern "C" void kernel_launch(void* const* d_in, const int* in_sizes, int n_in,
                              void* d_out, int out_size, void* d_ws, size_t ws_size,
                              hipStream_t stream) {
  const float* query = (const float*)d_in[0];
  const float* key   = (const float*)d_in[1];
  const float* value = (const float*)d_in[2];
  const float* W0    = (const float*)d_in[3];
  const float* b0    = (const float*)d_in[4];
  const float* Wout  = (const float*)d_in[5];
  const float* bout  = (const float*)d_in[6];
  float* out = (float*)d_out;

  char* ws = (char*)d_ws;
  const size_t PSZ = (size_t)32768 * 512 * 2;
  unsigned short* Pq  = (unsigned short*)(ws);            // later reused as AO
  unsigned short* Pk  = (unsigned short*)(ws + PSZ);
  unsigned short* Pv  = (unsigned short*)(ws + 2 * PSZ);
  unsigned short* Qm  = (unsigned short*)(ws + 3 * PSZ);
  unsigned short* Km  = (unsigned short*)(ws + 4 * PSZ);
  unsigned short* W0T = (unsigned short*)(ws + 5 * PSZ);
  unsigned short* WoT = (unsigned short*)(ws + 5 * PSZ + 524288);

  tcast2_k<<<2048, 256, 0, stream>>>(W0, W0T, Wout, WoT);
  proj3_k<<<1536, 512, 0, stream>>>(query, key, value, W0T, b0, Pq, Pk, Pv);
  localmix2_k<<<16384, 256, 0, stream>>>(Pq, Pk, b0, Qm, Km);
  attn_k<<<2048, 256, 0, stream>>>(Qm, Km, Pv, Pq /*AO*/);
  gemmout_k<<<512, 512, 0, stream>>>(Pq, WoT, bout, out);
}